// Round 1
// baseline (624.138 us; speedup 1.0000x reference)
//
#include <hip/hip_runtime.h>
#include <stdint.h>

// Contrast loss, fully fused on-GPU:
//  1) cast z/W to bf16
//  2) h  = ELU(z @ W1^T + b1)          (bf16 MFMA GEMM, bf16 out)
//  3) zp = h @ W2^T + b2               (bf16 MFMA GEMM, f32 out)
//  4) zn = zp / |zp|  (mp side also * 1/tau), bf16
//  5) S-tile = zn_mp @ zn_sc^T ; e = exp(S); fused masked row/col reductions
//     rowsum[i] += e; posrow[i] += e*pos[i,j]; colsum[j] += e; poscol[j] += e*pos[j,i]
//  6) out = -(1/N) * sum_i 0.5*(log(posrow/rowsum+eps) + log(poscol/colsum+eps))

#define NN 8192
#define HH 512
#define TAUF 0.8f
#define EPSF 1e-8f

typedef __attribute__((ext_vector_type(8))) short short8;
typedef __attribute__((ext_vector_type(4))) float f32x4;
typedef __attribute__((ext_vector_type(4))) int i32x4;
typedef __attribute__((ext_vector_type(4))) unsigned short u16x4;
typedef unsigned short u16;
typedef unsigned int u32;
typedef uint8_t u8;

typedef __attribute__((address_space(1))) void GV;
typedef __attribute__((address_space(3))) void LV;

__device__ __forceinline__ void g2l16(const void* g, void* l) {
  // async global->LDS, 16B per lane; LDS dest = wave-uniform base + lane*16
  __builtin_amdgcn_global_load_lds((const GV*)g, (LV*)l, 16, 0, 0);
}

__device__ __forceinline__ u16 f2bf(float x) {  // RNE f32->bf16
  u32 u = __builtin_bit_cast(u32, x);
  u = (u + 0x7fffu + ((u >> 16) & 1u)) >> 16;
  return (u16)u;
}

// ---------------- cast f32 -> bf16, 8 elems/thread ----------------
__global__ void cast_kernel(const float* __restrict__ in, u16* __restrict__ out, int n) {
  int i = (blockIdx.x * 256 + threadIdx.x) * 8;
  if (i >= n) return;
  f32x4 a = *(const f32x4*)(in + i);
  f32x4 b = *(const f32x4*)(in + i + 4);
  u16 o[8];
  o[0] = f2bf(a.x); o[1] = f2bf(a.y); o[2] = f2bf(a.z); o[3] = f2bf(a.w);
  o[4] = f2bf(b.x); o[5] = f2bf(b.y); o[6] = f2bf(b.z); o[7] = f2bf(b.w);
  i32x4 v;
  v.x = (int)(o[0] | ((u32)o[1] << 16)); v.y = (int)(o[2] | ((u32)o[3] << 16));
  v.z = (int)(o[4] | ((u32)o[5] << 16)); v.w = (int)(o[6] | ((u32)o[7] << 16));
  *(i32x4*)(out + i) = v;
}

// ---------------- projection GEMM: C = A @ W^T (+bias), tile 128x128, BK=32 ----------------
// EPI 0: ELU -> bf16 out ; EPI 1: bias -> f32 out
template <int EPI>
__global__ __launch_bounds__(256)
void gemm_proj(const u16* __restrict__ A1, const u16* __restrict__ A2,
               const u16* __restrict__ W, const float* __restrict__ bias,
               void* __restrict__ out1, void* __restrict__ out2) {
  __shared__ __align__(16) u16 As[128 * 32];
  __shared__ __align__(16) u16 Bs[128 * 32];
  const int tid = threadIdx.x;
  const int lane = tid & 63, w = tid >> 6;
  const int lo = lane & 15, quad = lane >> 4;
  const int wy = w >> 1, wx = w & 1;
  const u16* A; char* Out; int m0;
  if (blockIdx.y < 64) { A = A1; Out = (char*)out1; m0 = blockIdx.y * 128; }
  else                 { A = A2; Out = (char*)out2; m0 = (blockIdx.y - 64) * 128; }
  const int n0 = blockIdx.x * 128;
  const int srow = w * 16 + (lane >> 2);   // staging row (per round)
  const int skel = (lane & 3) * 8;         // staging k-element offset
  char* AsB = (char*)As; char* BsB = (char*)Bs;
  f32x4 acc[4][4] = {};

  for (int k0 = 0; k0 < HH; k0 += 32) {
    const u16* ga = A + (size_t)(m0 + srow) * HH + k0 + skel;
    const u16* gb = W + (size_t)(n0 + srow) * HH + k0 + skel;
    g2l16(ga, AsB + w * 1024);
    g2l16(ga + (size_t)64 * HH, AsB + w * 1024 + 4096);
    g2l16(gb, BsB + w * 1024);
    g2l16(gb + (size_t)64 * HH, BsB + w * 1024 + 4096);
    asm volatile("s_waitcnt vmcnt(0)" ::: "memory");
    __syncthreads();
    short8 aF[4], bF[4];
#pragma unroll
    for (int mi = 0; mi < 4; ++mi)
      aF[mi] = *(const short8*)(AsB + (wy * 64 + mi * 16 + lo) * 64 + quad * 16);
#pragma unroll
    for (int ni = 0; ni < 4; ++ni)
      bF[ni] = *(const short8*)(BsB + (wx * 64 + ni * 16 + lo) * 64 + quad * 16);
#pragma unroll
    for (int mi = 0; mi < 4; ++mi)
#pragma unroll
      for (int ni = 0; ni < 4; ++ni)
        acc[mi][ni] = __builtin_amdgcn_mfma_f32_16x16x32_bf16(aF[mi], bF[ni], acc[mi][ni], 0, 0, 0);
    __syncthreads();
  }
  // epilogue: D[row=quad*4+r][col=lo] per 16x16 tile
#pragma unroll
  for (int mi = 0; mi < 4; ++mi) {
    int rl = wy * 64 + mi * 16 + quad * 4;
#pragma unroll
    for (int ni = 0; ni < 4; ++ni) {
      int cl = wx * 64 + ni * 16 + lo;
      float bv = bias[n0 + cl];
#pragma unroll
      for (int r = 0; r < 4; ++r) {
        float v = acc[mi][ni][r] + bv;
        size_t idx = (size_t)(m0 + rl + r) * HH + (n0 + cl);
        if (EPI == 0) {
          if (v < 0.f) v = __expf(v) - 1.f;   // ELU
          ((u16*)Out)[idx] = f2bf(v);
        } else {
          ((float*)Out)[idx] = v;
        }
      }
    }
  }
}

// ---------------- row-normalize to bf16 (scale folds 1/tau on mp side) ----------------
__global__ void norm_kernel(const float* __restrict__ zp, u16* __restrict__ out, float scale) {
  const int row = blockIdx.x;
  const int t = threadIdx.x;  // 128 threads
  const float* src = zp + (size_t)row * HH;
  f32x4 v = *(const f32x4*)(src + t * 4);
  float ss = v.x * v.x + v.y * v.y + v.z * v.z + v.w * v.w;
#pragma unroll
  for (int d = 1; d < 64; d <<= 1) ss += __shfl_xor(ss, d, 64);
  __shared__ float red[2];
  if ((t & 63) == 0) red[t >> 6] = ss;
  __syncthreads();
  float inv = scale * rsqrtf(red[0] + red[1]);
  u16x4 o;
  o[0] = f2bf(v.x * inv); o[1] = f2bf(v.y * inv);
  o[2] = f2bf(v.z * inv); o[3] = f2bf(v.w * inv);
  *(u16x4*)(out + (size_t)row * HH + t * 4) = o;
}

// ---------------- similarity GEMM + fused exp + masked row/col reductions ----------------
__global__ __launch_bounds__(256)
void sim_kernel(const u16* __restrict__ Az, const u16* __restrict__ Bz,
                const int* __restrict__ pos,
                float* __restrict__ rowsum, float* __restrict__ posrow,
                float* __restrict__ colsum, float* __restrict__ poscol) {
  __shared__ __align__(16) u16 As[128 * 32];
  __shared__ __align__(16) u16 Bs[128 * 32];
  __shared__ __align__(16) u8 PB[128 * 136];  // pos[j0+jl][i0+il] bytes, pitch 136
  const int tid = threadIdx.x;
  const int lane = tid & 63, w = tid >> 6;
  const int lo = lane & 15, quad = lane >> 4;
  const int wy = w >> 1, wx = w & 1;
  const int i0 = blockIdx.y * 128, j0 = blockIdx.x * 128;
  const int srow = w * 16 + (lane >> 2);
  const int skel = (lane & 3) * 8;
  char* AsB = (char*)As; char* BsB = (char*)Bs;
  f32x4 acc[4][4] = {};

  for (int k0 = 0; k0 < HH; k0 += 32) {
    const u16* ga = Az + (size_t)(i0 + srow) * HH + k0 + skel;
    const u16* gb = Bz + (size_t)(j0 + srow) * HH + k0 + skel;
    g2l16(ga, AsB + w * 1024);
    g2l16(ga + (size_t)64 * HH, AsB + w * 1024 + 4096);
    g2l16(gb, BsB + w * 1024);
    g2l16(gb + (size_t)64 * HH, BsB + w * 1024 + 4096);
    asm volatile("s_waitcnt vmcnt(0)" ::: "memory");
    __syncthreads();
    short8 aF[4], bF[4];
#pragma unroll
    for (int mi = 0; mi < 4; ++mi)
      aF[mi] = *(const short8*)(AsB + (wy * 64 + mi * 16 + lo) * 64 + quad * 16);
#pragma unroll
    for (int ni = 0; ni < 4; ++ni)
      bF[ni] = *(const short8*)(BsB + (wx * 64 + ni * 16 + lo) * 64 + quad * 16);
#pragma unroll
    for (int mi = 0; mi < 4; ++mi)
#pragma unroll
      for (int ni = 0; ni < 4; ++ni)
        acc[mi][ni] = __builtin_amdgcn_mfma_f32_16x16x32_bf16(aF[mi], bF[ni], acc[mi][ni], 0, 0, 0);
    __syncthreads();
  }

  // stage pos^T tile into LDS as packed bytes: PB[jl*136 + il] = pos[j0+jl][i0+il]
#pragma unroll
  for (int it = 0; it < 16; ++it) {
    int chunk = tid + it * 256;          // 4096 chunks of 4 ints
    int jl = chunk >> 5;                 // 0..127
    int c4 = (chunk & 31) * 4;           // i_local
    i32x4 p = *(const i32x4*)(pos + (size_t)(j0 + jl) * NN + i0 + c4);
    u32 packed = ((u32)p.x & 1u) | (((u32)p.y & 1u) << 8) |
                 (((u32)p.z & 1u) << 16) | (((u32)p.w & 1u) << 24);
    *(u32*)(PB + jl * 136 + c4) = packed;
  }
  __syncthreads();

  // e = exp(cos/tau), in place
#pragma unroll
  for (int mi = 0; mi < 4; ++mi)
#pragma unroll
    for (int ni = 0; ni < 4; ++ni)
#pragma unroll
      for (int r = 0; r < 4; ++r)
        acc[mi][ni][r] = __expf(acc[mi][ni][r]);

  const int rowb = wy * 64 + quad * 4;
  const int colb = wx * 64 + lo;

  // row reductions (rowsum, posrow): pos[i][j] read direct from global (coalesced 16-lane runs)
#pragma unroll
  for (int mi = 0; mi < 4; ++mi) {
    int rl = rowb + mi * 16;
    float rs[4] = {0.f, 0.f, 0.f, 0.f}, pr[4] = {0.f, 0.f, 0.f, 0.f};
#pragma unroll
    for (int ni = 0; ni < 4; ++ni) {
      int cl = colb + ni * 16;
      const int* pg = pos + (size_t)(i0 + rl) * NN + (j0 + cl);
#pragma unroll
      for (int r = 0; r < 4; ++r) {
        float e = acc[mi][ni][r];
        rs[r] += e;
        int pv = pg[(size_t)r * NN];
        pr[r] += pv ? e : 0.0f;
      }
    }
#pragma unroll
    for (int d = 1; d < 16; d <<= 1) {
#pragma unroll
      for (int r = 0; r < 4; ++r) {
        rs[r] += __shfl_xor(rs[r], d, 64);
        pr[r] += __shfl_xor(pr[r], d, 64);
      }
    }
    if (lo == 0) {
#pragma unroll
      for (int r = 0; r < 4; ++r) {
        unsafeAtomicAdd(&rowsum[i0 + rl + r], rs[r]);
        unsafeAtomicAdd(&posrow[i0 + rl + r], pr[r]);
      }
    }
  }

  // col reductions (colsum, poscol): pos[j][i] from LDS bytes, u32 covers r=0..3
#pragma unroll
  for (int ni = 0; ni < 4; ++ni) {
    int cl = colb + ni * 16;
    float cs = 0.f, pc = 0.f;
#pragma unroll
    for (int mi = 0; mi < 4; ++mi) {
      int rl = rowb + mi * 16;
      u32 pb4 = *(const u32*)(PB + cl * 136 + rl);
#pragma unroll
      for (int r = 0; r < 4; ++r) {
        float e = acc[mi][ni][r];
        cs += e;
        pc += ((pb4 >> (8 * r)) & 1u) ? e : 0.0f;
      }
    }
    cs += __shfl_xor(cs, 16, 64); cs += __shfl_xor(cs, 32, 64);
    pc += __shfl_xor(pc, 16, 64); pc += __shfl_xor(pc, 32, 64);
    if (quad == 0) {
      unsafeAtomicAdd(&colsum[j0 + cl], cs);
      unsafeAtomicAdd(&poscol[j0 + cl], pc);
    }
  }
}

// ---------------- final scalar reduce ----------------
__global__ void final_kernel(const float* __restrict__ rowsum, const float* __restrict__ posrow,
                             const float* __restrict__ colsum, const float* __restrict__ poscol,
                             float* __restrict__ out) {
  float s = 0.f;
  for (int i = threadIdx.x; i < NN; i += 256) {
    s += __logf(posrow[i] / (rowsum[i] + EPSF));
    s += __logf(poscol[i] / (colsum[i] + EPSF));
  }
#pragma unroll
  for (int d = 1; d < 64; d <<= 1) s += __shfl_xor(s, d, 64);
  __shared__ float red[4];
  if ((threadIdx.x & 63) == 0) red[threadIdx.x >> 6] = s;
  __syncthreads();
  if (threadIdx.x == 0)
    out[0] = -0.5f * (red[0] + red[1] + red[2] + red[3]) / (float)NN;
}

extern "C" void kernel_launch(void* const* d_in, const int* in_sizes, int n_in,
                              void* d_out, int out_size, void* d_ws, size_t ws_size,
                              hipStream_t stream) {
  const float* z_mp = (const float*)d_in[0];
  const float* z_sc = (const float*)d_in[1];
  const int* pos = (const int*)d_in[2];
  const float* W1 = (const float*)d_in[3];
  const float* b1 = (const float*)d_in[4];
  const float* W2 = (const float*)d_in[5];
  const float* b2 = (const float*)d_in[6];
  float* out = (float*)d_out;

  char* ws = (char*)d_ws;
  u16* zbA = (u16*)(ws);                      // 8 MB
  u16* zbB = (u16*)(ws + 8388608);            // 8 MB
  u16* W1b = (u16*)(ws + 16777216);           // 0.5 MB
  u16* W2b = (u16*)(ws + 17301504);           // 0.5 MB
  u16* hA  = (u16*)(ws + 17825792);           // 8 MB
  u16* hB  = (u16*)(ws + 26214400);           // 8 MB
  float* zpA = (float*)(ws + 34603008);       // 16 MB
  float* zpB = (float*)(ws + 51380224);       // 16 MB
  u16* znA = (u16*)(ws + 68157440);           // 8 MB
  u16* znB = (u16*)(ws + 76546048);           // 8 MB
  float* rowsum = (float*)(ws + 84934656);    // 4 x 32 KB
  float* posrow = rowsum + NN;
  float* colsum = rowsum + 2 * NN;
  float* poscol = rowsum + 3 * NN;

  cast_kernel<<<2048, 256, 0, stream>>>(z_mp, zbA, NN * HH);
  cast_kernel<<<2048, 256, 0, stream>>>(z_sc, zbB, NN * HH);
  cast_kernel<<<128, 256, 0, stream>>>(W1, W1b, HH * HH);
  cast_kernel<<<128, 256, 0, stream>>>(W2, W2b, HH * HH);

  dim3 gp(4, 128);
  gemm_proj<0><<<gp, 256, 0, stream>>>(zbA, zbB, W1b, b1, hA, hB);
  gemm_proj<1><<<gp, 256, 0, stream>>>(hA, hB, W2b, b2, zpA, zpB);

  norm_kernel<<<NN, 128, 0, stream>>>(zpA, znA, 1.0f / TAUF);
  norm_kernel<<<NN, 128, 0, stream>>>(zpB, znB, 1.0f);

  hipMemsetAsync(rowsum, 0, 4 * NN * sizeof(float), stream);

  dim3 gs(64, 64);
  sim_kernel<<<gs, 256, 0, stream>>>(znA, znB, pos, rowsum, posrow, colsum, poscol);
  final_kernel<<<1, 256, 0, stream>>>(rowsum, posrow, colsum, poscol, out);
}